// Round 2
// baseline (92.152 us; speedup 1.0000x reference)
//
#include <hip/hip_runtime.h>
#include <math.h>

#define NSEG   262144   // fullpath has 262145 points -> 262144 segments
#define NVERT  17

struct Consts {
  float qx[NVERT], qy[NVERT], sx[NVERT], sy[NVERT];  // wzy: vertex + edge vector
  float dx[NVERT], dy[NVERT], c0[NVERT];             // fxy: unit normal + (0.1 - q.d)
};

__launch_bounds__(256, 8)
__global__ void path_cost_kernel(const float2* __restrict__ path,
                                 const float2* __restrict__ st,
                                 const float2* __restrict__ en,
                                 float* __restrict__ out,
                                 Consts K) {
  const int lane = threadIdx.x & 127;          // segment within block
  const int half = threadIdx.x >> 7;           // 0: samples 1..15, 1: samples 16..30
  const int i = blockIdx.x * 128 + lane;       // segment id (grid covers exactly)

  const float2 a = (i == 0)        ? *st : path[i - 1];
  const float2 b = (i == NSEG - 1) ? *en : path[i];
  const float rx = b.x - a.x, ry = b.y - a.y;

  float wzy = 0.f, fxy0 = 0.f, fxy1 = 0.f, lp = 0.f;

  // ---- wzy: segment-edge intersection indicator, split 8/9 edges per half ----
  auto edge_test = [&](int e) -> float {
    const float qpx = K.qx[e] - a.x;
    const float qpy = K.qy[e] - a.y;
    const float den = fmaf(rx, K.sy[e], fmaf(-ry, K.sx[e], 1e-8f));
    const float nt  = qpx * K.sy[e] - qpy * K.sx[e];
    const float nu  = qpx * ry - qpy * rx;
    const bool hit = (nt * den > 0.f) && ((nt - den) * den < 0.f) &&
                     (nu * den > 0.f) && ((nu - den) * den < 0.f);
    return hit ? 1.f : 0.f;
  };
  if (half == 0) {
    #pragma unroll
    for (int e = 0; e < 8; ++e) wzy += edge_test(e);
    lp = sqrtf(fmaf(ry, ry, fmaf(rx, rx, 1e-6f)));
  } else {
    #pragma unroll
    for (int e = 8; e < NVERT; ++e) wzy += edge_test(e);
  }

  // ---- fxy: per-edge value is affine in sample fraction f: val_e = A_e + f*B_e ----
  float A[NVERT], Bc[NVERT];
  #pragma unroll
  for (int e = 0; e < NVERT; ++e) {
    A[e]  = fmaf(a.x, K.dx[e], fmaf(a.y, K.dy[e], K.c0[e]));
    Bc[e] = fmaf(rx, K.dx[e], ry * K.dy[e]);
  }
  // sample multiset {1.0, 1/30..29/30} == {k/30, k=1..30}; half0 k=1..15, half1 k=16..30
  const float f0 = half ? (16.0f / 30.0f) : (1.0f / 30.0f);
  #pragma unroll
  for (int j = 0; j < 15; ++j) {
    const float f = f0 + (float)j * (1.0f / 30.0f);
    float pr0 = 1.f, pr1 = 1.f, pr2 = 1.f, pr3 = 1.f;
    #pragma unroll
    for (int e = 0; e < 5; ++e)   pr0 *= fmaxf(fmaf(f, Bc[e], A[e]), 0.f);
    #pragma unroll
    for (int e = 5; e < 10; ++e)  pr1 *= fmaxf(fmaf(f, Bc[e], A[e]), 0.f);
    #pragma unroll
    for (int e = 10; e < 13; ++e) pr2 *= fmaxf(fmaf(f, Bc[e], A[e]), 0.f);
    #pragma unroll
    for (int e = 13; e < 17; ++e) pr3 *= fmaxf(fmaf(f, Bc[e], A[e]), 0.f);
    if (j & 1) fxy1 += (pr0 + pr1) + (pr2 + pr3);
    else       fxy0 += (pr0 + pr1) + (pr2 + pr3);
  }
  float fxy = fxy0 + fxy1;

  // ---- reduction: wave64 shuffle -> LDS -> one atomic per block per output ----
  #pragma unroll
  for (int o = 32; o > 0; o >>= 1) {
    wzy += __shfl_down(wzy, o);
    fxy += __shfl_down(fxy, o);
    lp  += __shfl_down(lp,  o);
  }
  __shared__ float sm[3][4];  // 256 threads = 4 waves
  const int wid = threadIdx.x >> 6;
  if ((threadIdx.x & 63) == 0) { sm[0][wid] = wzy; sm[1][wid] = fxy; sm[2][wid] = lp; }
  __syncthreads();
  if (threadIdx.x == 0) {
    atomicAdd(&out[0], (sm[0][0] + sm[0][1]) + (sm[0][2] + sm[0][3]));
    atomicAdd(&out[1], (sm[1][0] + sm[1][1]) + (sm[1][2] + sm[1][3]));
    atomicAdd(&out[2], (sm[2][0] + sm[2][1]) + (sm[2][2] + sm[2][3]));
  }
}

extern "C" void kernel_launch(void* const* d_in, const int* in_sizes, int n_in,
                              void* d_out, int out_size, void* d_ws, size_t ws_size,
                              hipStream_t stream) {
  (void)in_sizes; (void)n_in; (void)out_size; (void)d_ws; (void)ws_size;

  static const int   cnt[4] = {5, 5, 3, 4};
  static const float VX[NVERT] = {1.23f, 1.75f, 2.1f,  1.58f, 1.4f,
                                  4.65f, 4.0f,  4.52f, 5.06f, 5.9f,
                                  6.78f, 7.78f, 7.78f,
                                  4.0f,  4.35f, 4.8f,  4.37f};
  static const float VY[NVERT] = {3.47f, 4.0f,  3.63f, 2.3f,  2.67f,
                                  5.98f, 6.48f, 7.68f, 7.73f, 6.95f,
                                  3.4f,  5.1f,  3.76f,
                                  3.0f,  3.35f, 3.45f, 2.75f};

  Consts K;
  int base = 0;
  for (int ob = 0; ob < 4; ++ob) {
    for (int j = 0; j < cnt[ob]; ++j) {
      const int e = base + j;
      const int n = base + ((j + 1) % cnt[ob]);
      const float sx = VX[n] - VX[e], sy = VY[n] - VY[e];
      K.qx[e] = VX[e]; K.qy[e] = VY[e]; K.sx[e] = sx; K.sy[e] = sy;
      float dx = sy, dy = -sx;
      const float nrm = sqrtf(dx * dx + dy * dy);
      dx /= nrm; dy /= nrm;
      K.dx[e] = dx; K.dy[e] = dy;
      K.c0[e] = 0.1f - (VX[e] * dx + VY[e] * dy);
    }
    base += cnt[ob];
  }

  const float2* path = (const float2*)d_in[0];  // (262143, 2) f32
  const float2* st   = (const float2*)d_in[1];  // (2,) f32
  const float2* en   = (const float2*)d_in[2];  // (2,) f32
  float* out = (float*)d_out;                   // 3 f32

  hipMemsetAsync(out, 0, 3 * sizeof(float), stream);
  path_cost_kernel<<<NSEG / 128, 256, 0, stream>>>(path, st, en, out, K);
}

// Round 3
// 52.910 us; speedup vs baseline: 1.7417x; 1.7417x over previous
//
#include <hip/hip_runtime.h>
#include <math.h>

#define NSEG  262144   // fullpath has 262145 points -> 262144 segments
#define NVERT 17

typedef float v2f __attribute__((ext_vector_type(2)));

// ---------------- compile-time geometry (folds to inline literals) ----------
struct EdgeC { float qx, qy, sx, sy, dx, dy, c0; };

constexpr double csqrt_(double x) {
  double g = x > 1.0 ? x : 1.0;
  for (int i = 0; i < 64; ++i) g = 0.5 * (g + x / g);
  return g;
}
constexpr EdgeC mkedge(double qx, double qy, double nx, double ny) {
  double sx = nx - qx, sy = ny - qy;
  double n = csqrt_(sx * sx + sy * sy);
  double dx = sy / n, dy = -sx / n;
  return EdgeC{(float)qx, (float)qy, (float)sx, (float)sy,
               (float)dx, (float)dy, (float)(0.1 - (qx * dx + qy * dy))};
}
constexpr EdgeC E[NVERT] = {
  // obstacle 0 (5)
  mkedge(1.23,3.47, 1.75,4.0), mkedge(1.75,4.0, 2.1,3.63), mkedge(2.1,3.63, 1.58,2.3),
  mkedge(1.58,2.3, 1.4,2.67),  mkedge(1.4,2.67, 1.23,3.47),
  // obstacle 1 (5)
  mkedge(4.65,5.98, 4.0,6.48), mkedge(4.0,6.48, 4.52,7.68), mkedge(4.52,7.68, 5.06,7.73),
  mkedge(5.06,7.73, 5.9,6.95), mkedge(5.9,6.95, 4.65,5.98),
  // obstacle 2 (3)
  mkedge(6.78,3.4, 7.78,5.1),  mkedge(7.78,5.1, 7.78,3.76), mkedge(7.78,3.76, 6.78,3.4),
  // obstacle 3 (4)
  mkedge(4.0,3.0, 4.35,3.35),  mkedge(4.35,3.35, 4.8,3.45), mkedge(4.8,3.45, 4.37,2.75),
  mkedge(4.37,2.75, 4.0,3.0)
};

__global__ __launch_bounds__(256)
void path_cost_kernel(const float2* __restrict__ path,
                      const float2* __restrict__ st,
                      const float2* __restrict__ en,
                      float* __restrict__ out) {
  const int i = blockIdx.x * 256 + threadIdx.x;   // segment id (grid covers exactly)

  const float2 a = (i == 0)        ? *st : path[i - 1];
  const float2 b = (i == NSEG - 1) ? *en : path[i];
  const float rx = b.x - a.x, ry = b.y - a.y;

  const float lp = sqrtf(fmaf(ry, ry, fmaf(rx, rx, 1e-6f)));

  // ---- wzy: 0<t<1 && 0<u<1  <=>  min(nt,nu)>min(0,den) && max(nt,nu)<max(0,den)
  int hits = 0;
  #pragma unroll
  for (int e = 0; e < NVERT; ++e) {
    const float qpx = E[e].qx - a.x;
    const float qpy = E[e].qy - a.y;
    const float den = fmaf(rx, E[e].sy, fmaf(-ry, E[e].sx, 1e-8f));
    const float nt  = fmaf(qpx, E[e].sy, -(qpy * E[e].sx));
    const float nu  = fmaf(qpx, ry, -(qpy * rx));
    const float mn  = fminf(nt, nu);
    const float mx  = fmaxf(nt, nu);
    hits += (mn > fminf(0.f, den)) && (mx < fmaxf(0.f, den));
  }

  // ---- fxy: edge value affine in fraction f: val = A[e] + f*B[e] ----
  float A[NVERT], B[NVERT];
  #pragma unroll
  for (int e = 0; e < NVERT; ++e) {
    A[e] = fmaf(a.x, E[e].dx, fmaf(a.y, E[e].dy, E[e].c0));
    B[e] = fmaf(rx, E[e].dx, ry * E[e].dy);
  }
  // sample multiset {1.0, 1/30..29/30} == {k/30, k=1..30}; pack (k, k+15)
  v2f f2   = {1.0f / 30.0f, 16.0f / 30.0f};
  v2f acc0 = {0.f, 0.f}, acc1 = {0.f, 0.f};
  #pragma unroll
  for (int jp = 0; jp < 15; ++jp) {
    v2f p0 = {1.f, 1.f}, p1 = {1.f, 1.f}, p2 = {1.f, 1.f}, p3 = {1.f, 1.f};
    #pragma unroll
    for (int e = 0; e < 5; ++e)   p0 *= __builtin_elementwise_max(f2 * B[e] + A[e], (v2f)0.f);
    #pragma unroll
    for (int e = 5; e < 10; ++e)  p1 *= __builtin_elementwise_max(f2 * B[e] + A[e], (v2f)0.f);
    #pragma unroll
    for (int e = 10; e < 13; ++e) p2 *= __builtin_elementwise_max(f2 * B[e] + A[e], (v2f)0.f);
    #pragma unroll
    for (int e = 13; e < 17; ++e) p3 *= __builtin_elementwise_max(f2 * B[e] + A[e], (v2f)0.f);
    if (jp & 1) acc1 += (p0 + p1) + (p2 + p3);
    else        acc0 += (p0 + p1) + (p2 + p3);
    f2 += 1.0f / 30.0f;
  }
  float fxy = (acc0.x + acc0.y) + (acc1.x + acc1.y);
  float wzy = (float)hits;
  float lpv = lp;

  // ---- reduction: wave64 shuffle -> LDS -> one atomic per block per output ----
  #pragma unroll
  for (int o = 32; o > 0; o >>= 1) {
    wzy += __shfl_down(wzy, o);
    fxy += __shfl_down(fxy, o);
    lpv += __shfl_down(lpv, o);
  }
  __shared__ float sm[3][4];  // 256 threads = 4 waves
  const int wid = threadIdx.x >> 6;
  if ((threadIdx.x & 63) == 0) { sm[0][wid] = wzy; sm[1][wid] = fxy; sm[2][wid] = lpv; }
  __syncthreads();
  if (threadIdx.x == 0) {
    atomicAdd(&out[0], (sm[0][0] + sm[0][1]) + (sm[0][2] + sm[0][3]));
    atomicAdd(&out[1], (sm[1][0] + sm[1][1]) + (sm[1][2] + sm[1][3]));
    atomicAdd(&out[2], (sm[2][0] + sm[2][1]) + (sm[2][2] + sm[2][3]));
  }
}

extern "C" void kernel_launch(void* const* d_in, const int* in_sizes, int n_in,
                              void* d_out, int out_size, void* d_ws, size_t ws_size,
                              hipStream_t stream) {
  (void)in_sizes; (void)n_in; (void)out_size; (void)d_ws; (void)ws_size;

  const float2* path = (const float2*)d_in[0];  // (262143, 2) f32
  const float2* st   = (const float2*)d_in[1];  // (2,) f32
  const float2* en   = (const float2*)d_in[2];  // (2,) f32
  float* out = (float*)d_out;                   // 3 f32

  hipMemsetAsync(out, 0, 3 * sizeof(float), stream);
  path_cost_kernel<<<NSEG / 256, 256, 0, stream>>>(path, st, en, out);
}

// Round 4
// 17.377 us; speedup vs baseline: 5.3030x; 3.0448x over previous
//
#include <hip/hip_runtime.h>
#include <math.h>

#define NSEG   262144   // fullpath has 262145 points -> 262144 segments
#define NVERT  17
#define NBLK   1024     // NSEG / 256

typedef float v2f __attribute__((ext_vector_type(2)));

// ---------------- compile-time geometry (folds to inline literals) ----------
struct EdgeC { float qx, qy, sx, sy, dx, dy, c0; };

constexpr double csqrt_(double x) {
  double g = x > 1.0 ? x : 1.0;
  for (int i = 0; i < 64; ++i) g = 0.5 * (g + x / g);
  return g;
}
constexpr EdgeC mkedge(double qx, double qy, double nx, double ny) {
  double sx = nx - qx, sy = ny - qy;
  double n = csqrt_(sx * sx + sy * sy);
  double dx = sy / n, dy = -sx / n;
  return EdgeC{(float)qx, (float)qy, (float)sx, (float)sy,
               (float)dx, (float)dy, (float)(0.1 - (qx * dx + qy * dy))};
}
constexpr EdgeC E[NVERT] = {
  // obstacle 0 (5)
  mkedge(1.23,3.47, 1.75,4.0), mkedge(1.75,4.0, 2.1,3.63), mkedge(2.1,3.63, 1.58,2.3),
  mkedge(1.58,2.3, 1.4,2.67),  mkedge(1.4,2.67, 1.23,3.47),
  // obstacle 1 (5)
  mkedge(4.65,5.98, 4.0,6.48), mkedge(4.0,6.48, 4.52,7.68), mkedge(4.52,7.68, 5.06,7.73),
  mkedge(5.06,7.73, 5.9,6.95), mkedge(5.9,6.95, 4.65,5.98),
  // obstacle 2 (3)
  mkedge(6.78,3.4, 7.78,5.1),  mkedge(7.78,5.1, 7.78,3.76), mkedge(7.78,3.76, 6.78,3.4),
  // obstacle 3 (4)
  mkedge(4.0,3.0, 4.35,3.35),  mkedge(4.35,3.35, 4.8,3.45), mkedge(4.8,3.45, 4.37,2.75),
  mkedge(4.37,2.75, 4.0,3.0)
};

__global__ __launch_bounds__(256)
void path_cost_kernel(const float2* __restrict__ path,
                      const float2* __restrict__ st,
                      const float2* __restrict__ en,
                      float* __restrict__ ws) {
  const int i = blockIdx.x * 256 + threadIdx.x;   // segment id (grid covers exactly)

  const float2 a = (i == 0)        ? *st : path[i - 1];
  const float2 b = (i == NSEG - 1) ? *en : path[i];
  const float rx = b.x - a.x, ry = b.y - a.y;

  float lpv = sqrtf(fmaf(ry, ry, fmaf(rx, rx, 1e-6f)));

  // ---- wzy: 0<t<1 && 0<u<1  <=>  min(nt,nu)>min(0,den) && max(nt,nu)<max(0,den)
  int hits = 0;
  #pragma unroll
  for (int e = 0; e < NVERT; ++e) {
    const float qpx = E[e].qx - a.x;
    const float qpy = E[e].qy - a.y;
    const float den = fmaf(rx, E[e].sy, fmaf(-ry, E[e].sx, 1e-8f));
    const float nt  = fmaf(qpx, E[e].sy, -(qpy * E[e].sx));
    const float nu  = fmaf(qpx, ry, -(qpy * rx));
    const float mn  = fminf(nt, nu);
    const float mx  = fmaxf(nt, nu);
    hits += (mn > fminf(0.f, den)) && (mx < fmaxf(0.f, den));
  }
  float wzy = (float)hits;

  // ---- fxy: edge value affine in fraction f: val = A[e] + f*B[e] ----
  float A[NVERT], B[NVERT];
  #pragma unroll
  for (int e = 0; e < NVERT; ++e) {
    A[e] = fmaf(a.x, E[e].dx, fmaf(a.y, E[e].dy, E[e].c0));
    B[e] = fmaf(rx, E[e].dx, ry * E[e].dy);
  }
  // sample multiset {1.0, 1/30..29/30} == {k/30, k=1..30}; pack (k, k+15)
  v2f f2   = {1.0f / 30.0f, 16.0f / 30.0f};
  v2f acc0 = {0.f, 0.f}, acc1 = {0.f, 0.f};
  #pragma unroll
  for (int jp = 0; jp < 15; ++jp) {
    v2f p0 = {1.f, 1.f}, p1 = {1.f, 1.f}, p2 = {1.f, 1.f}, p3 = {1.f, 1.f};
    #pragma unroll
    for (int e = 0; e < 5; ++e)   p0 *= __builtin_elementwise_max(f2 * B[e] + A[e], (v2f)0.f);
    #pragma unroll
    for (int e = 5; e < 10; ++e)  p1 *= __builtin_elementwise_max(f2 * B[e] + A[e], (v2f)0.f);
    #pragma unroll
    for (int e = 10; e < 13; ++e) p2 *= __builtin_elementwise_max(f2 * B[e] + A[e], (v2f)0.f);
    #pragma unroll
    for (int e = 13; e < 17; ++e) p3 *= __builtin_elementwise_max(f2 * B[e] + A[e], (v2f)0.f);
    if (jp & 1) acc1 += (p0 + p1) + (p2 + p3);
    else        acc0 += (p0 + p1) + (p2 + p3);
    f2 += 1.0f / 30.0f;
  }
  float fxy = (acc0.x + acc0.y) + (acc1.x + acc1.y);

  // ---- reduction: wave64 shuffle -> LDS -> per-block partials (NO atomics) ----
  #pragma unroll
  for (int o = 32; o > 0; o >>= 1) {
    wzy += __shfl_down(wzy, o);
    fxy += __shfl_down(fxy, o);
    lpv += __shfl_down(lpv, o);
  }
  __shared__ float sm[3][4];  // 256 threads = 4 waves
  const int wid = threadIdx.x >> 6;
  if ((threadIdx.x & 63) == 0) { sm[0][wid] = wzy; sm[1][wid] = fxy; sm[2][wid] = lpv; }
  __syncthreads();
  if (threadIdx.x == 0) {
    ws[0 * NBLK + blockIdx.x] = (sm[0][0] + sm[0][1]) + (sm[0][2] + sm[0][3]);
    ws[1 * NBLK + blockIdx.x] = (sm[1][0] + sm[1][1]) + (sm[1][2] + sm[1][3]);
    ws[2 * NBLK + blockIdx.x] = (sm[2][0] + sm[2][1]) + (sm[2][2] + sm[2][3]);
  }
}

__global__ __launch_bounds__(256)
void reduce_kernel(const float* __restrict__ ws, float* __restrict__ out) {
  const int t = threadIdx.x;  // 256 threads, one block
  float w = 0.f, f = 0.f, l = 0.f;
  #pragma unroll
  for (int j = 0; j < 4; ++j) {
    w += ws[0 * NBLK + t + j * 256];
    f += ws[1 * NBLK + t + j * 256];
    l += ws[2 * NBLK + t + j * 256];
  }
  #pragma unroll
  for (int o = 32; o > 0; o >>= 1) {
    w += __shfl_down(w, o);
    f += __shfl_down(f, o);
    l += __shfl_down(l, o);
  }
  __shared__ float sm[3][4];
  const int wid = t >> 6;
  if ((t & 63) == 0) { sm[0][wid] = w; sm[1][wid] = f; sm[2][wid] = l; }
  __syncthreads();
  if (t == 0) {
    out[0] = (sm[0][0] + sm[0][1]) + (sm[0][2] + sm[0][3]);
    out[1] = (sm[1][0] + sm[1][1]) + (sm[1][2] + sm[1][3]);
    out[2] = (sm[2][0] + sm[2][1]) + (sm[2][2] + sm[2][3]);
  }
}

extern "C" void kernel_launch(void* const* d_in, const int* in_sizes, int n_in,
                              void* d_out, int out_size, void* d_ws, size_t ws_size,
                              hipStream_t stream) {
  (void)in_sizes; (void)n_in; (void)out_size; (void)ws_size;

  const float2* path = (const float2*)d_in[0];  // (262143, 2) f32
  const float2* st   = (const float2*)d_in[1];  // (2,) f32
  const float2* en   = (const float2*)d_in[2];  // (2,) f32
  float* ws  = (float*)d_ws;                    // 3 * NBLK partials
  float* out = (float*)d_out;                   // 3 f32

  path_cost_kernel<<<NBLK, 256, 0, stream>>>(path, st, en, ws);
  reduce_kernel<<<1, 256, 0, stream>>>(ws, out);
}